// Round 2
// baseline (1144.172 us; speedup 1.0000x reference)
//
#include <hip/hip_runtime.h>
#include <hip/hip_bf16.h>

typedef __hip_bfloat16 bf16;

#define SEQ   2048
#define DIM   10
#define VOC   32000
#define NROW  8192

__device__ __forceinline__ float bfr(unsigned short u) {
    return __uint_as_float(((unsigned)u) << 16);
}

// ---------------------------------------------------------------------------
// Kernel P: dtype probe. Even-indexed u16s of a genuine-bf16 N(0,1) tensor all
// have exponents near 127; for f32 data they are uniform mantissa bits (~24%
// sane). flag=1 -> bf16 inputs/output, flag=0 -> f32.
// ---------------------------------------------------------------------------
__global__ void probe_kernel(const unsigned short* __restrict__ raw,
                             int* __restrict__ flag) {
    if (blockIdx.x == 0 && threadIdx.x == 0) {
        int sane = 0;
        for (int i = 0; i < 64; i++) {
            unsigned short u = raw[2 * i];
            int e = (u >> 7) & 0xFF;
            if (u == 0 || (e >= 97 && e <= 157)) sane++;   // |v| in [2^-30, 2^30]
        }
        *flag = (sane >= 48) ? 1 : 0;
    }
}

// ---------------------------------------------------------------------------
// Kernel 1: h = emb[x] + pos;  Q/K/V = h @ W{q,k,v}^T   (f32 to workspace)
// ---------------------------------------------------------------------------
__global__ __launch_bounds__(256) void qkv_kernel(
    const int* __restrict__ x, const void* __restrict__ embp,
    const void* __restrict__ posp,
    const void* __restrict__ Wqp, const void* __restrict__ Wkp,
    const void* __restrict__ Wvp, const int* __restrict__ flag,
    float* __restrict__ Q, float* __restrict__ K, float* __restrict__ V) {
    __shared__ float wq[DIM * DIM], wk[DIM * DIM], wv[DIM * DIM];
    const int isbf = *flag;
    int t = threadIdx.x;
    if (t < DIM * DIM) {
        if (isbf) {
            wq[t] = bfr(((const unsigned short*)Wqp)[t]);
            wk[t] = bfr(((const unsigned short*)Wkp)[t]);
            wv[t] = bfr(((const unsigned short*)Wvp)[t]);
        } else {
            wq[t] = ((const float*)Wqp)[t];
            wk[t] = ((const float*)Wkp)[t];
            wv[t] = ((const float*)Wvp)[t];
        }
    }
    __syncthreads();
    int row = blockIdx.x * 256 + t;     // 32 blocks * 256 = 8192 exactly
    int s = row & (SEQ - 1);
    int tok = x[row];
    float h[DIM];
    if (isbf) {
        const unsigned short* e = (const unsigned short*)embp + (size_t)tok * DIM;
        const unsigned short* p = (const unsigned short*)posp + (size_t)s * DIM;
#pragma unroll
        for (int j = 0; j < DIM; j++) h[j] = bfr(e[j]) + bfr(p[j]);
    } else {
        const float* e = (const float*)embp + (size_t)tok * DIM;
        const float* p = (const float*)posp + (size_t)s * DIM;
#pragma unroll
        for (int j = 0; j < DIM; j++) h[j] = e[j] + p[j];
    }
#pragma unroll
    for (int i = 0; i < DIM; i++) {
        float aq = 0.f, ak = 0.f, av = 0.f;
#pragma unroll
        for (int j = 0; j < DIM; j++) {
            aq += h[j] * wq[i * DIM + j];
            ak += h[j] * wk[i * DIM + j];
            av += h[j] * wv[i * DIM + j];
        }
        Q[row * DIM + i] = aq;
        K[row * DIM + i] = ak;
        V[row * DIM + i] = av;
    }
}

// ---------------------------------------------------------------------------
// Kernel 2: causal attention, one wave (64 lanes) per query row.
// Each lane owns keys t = lane + 64*i, i in [0,32). Masked keys -> -1e30 ->
// exp()==0, matching ref's mask-before-scale (-1e9/sqrt(10) underflows too).
// O may alias Q: each wave reads only its own Q row, before writing O to it.
// ---------------------------------------------------------------------------
__global__ __launch_bounds__(256) void attn_kernel(
    const float* __restrict__ Q, const float* __restrict__ K,
    const float* __restrict__ V, float* __restrict__ O) {
    int wave = threadIdx.x >> 6;
    int lane = threadIdx.x & 63;
    int row = blockIdx.x * 4 + wave;       // 2048 blocks * 4 = 8192
    int b = row >> 11;
    int s = row & (SEQ - 1);

    const float* qp = Q + row * DIM;
    float q[DIM];
#pragma unroll
    for (int d = 0; d < DIM; d++) q[d] = qp[d];

    const float scale = 0.3162277660168379f;  // 1/sqrt(10)
    const float* Kb = K + (size_t)(b * SEQ) * DIM;
    const float* Vb = V + (size_t)(b * SEQ) * DIM;

    float sc[32];
#pragma unroll
    for (int i = 0; i < 32; i++) {
        int t = lane + (i << 6);
        const float2* kp = (const float2*)(Kb + t * DIM);  // t*10 even -> 8B aligned
        float2 k0 = kp[0], k1 = kp[1], k2 = kp[2], k3 = kp[3], k4 = kp[4];
        float acc = q[0] * k0.x + q[1] * k0.y + q[2] * k1.x + q[3] * k1.y +
                    q[4] * k2.x + q[5] * k2.y + q[6] * k3.x + q[7] * k3.y +
                    q[8] * k4.x + q[9] * k4.y;
        sc[i] = (t <= s) ? acc * scale : -1e30f;
    }
    float m = sc[0];
#pragma unroll
    for (int i = 1; i < 32; i++) m = fmaxf(m, sc[i]);
#pragma unroll
    for (int off = 32; off; off >>= 1) m = fmaxf(m, __shfl_xor(m, off, 64));

    float sum = 0.f;
    float o[DIM];
#pragma unroll
    for (int d = 0; d < DIM; d++) o[d] = 0.f;
#pragma unroll
    for (int i = 0; i < 32; i++) {
        float p = __expf(sc[i] - m);   // exp(-huge) == 0 for masked keys
        sum += p;
        int t = lane + (i << 6);
        const float2* vp = (const float2*)(Vb + t * DIM);
        float2 v0 = vp[0], v1 = vp[1], v2 = vp[2], v3 = vp[3], v4 = vp[4];
        o[0] += p * v0.x; o[1] += p * v0.y;
        o[2] += p * v1.x; o[3] += p * v1.y;
        o[4] += p * v2.x; o[5] += p * v2.y;
        o[6] += p * v3.x; o[7] += p * v3.y;
        o[8] += p * v4.x; o[9] += p * v4.y;
    }
#pragma unroll
    for (int off = 32; off; off >>= 1) {
        sum += __shfl_xor(sum, off, 64);
#pragma unroll
        for (int d = 0; d < DIM; d++) o[d] += __shfl_xor(o[d], off, 64);
    }
    if (lane == 0) {
        float inv = 1.0f / sum;
#pragma unroll
        for (int d = 0; d < DIM; d++) O[row * DIM + d] = o[d] * inv;
    }
}

// ---------------------------------------------------------------------------
// Kernel 3: logits = O @ Wo^T. The HBM-write bottleneck (512 MB bf16 / 1 GB f32).
// Block: 256 threads; 8 rows x 2048 vocab; 8 consecutive vocab per thread so
// the thread's Wo slice is contiguous (160 B bf16 = 10 uint4 loads).
// ---------------------------------------------------------------------------
#define RPB 8
#define VPT 8
__global__ __launch_bounds__(256) void logits_kernel(
    const float* __restrict__ O, const void* __restrict__ Wop,
    const int* __restrict__ flag, void* __restrict__ outp) {
    __shared__ float hrow[RPB][DIM];
    const int isbf = *flag;
    int t = threadIdx.x;
    if (t < RPB * DIM) {
        int r = t / DIM, d = t - r * DIM;
        hrow[r][d] = O[(size_t)(blockIdx.y * RPB + r) * DIM + d];
    }
    __syncthreads();

    int v0 = blockIdx.x * (256 * VPT) + t * VPT;
    if (v0 >= VOC) return;

    float w[VPT][DIM];
    if (isbf) {
        union { uint4 q[10]; unsigned short us[VPT * DIM]; } wr;
        const uint4* p = (const uint4*)((const unsigned short*)Wop + (size_t)v0 * DIM);
#pragma unroll
        for (int k = 0; k < 10; k++) wr.q[k] = p[k];
#pragma unroll
        for (int j = 0; j < VPT; j++)
#pragma unroll
            for (int d = 0; d < DIM; d++) w[j][d] = bfr(wr.us[j * DIM + d]);
    } else {
        union { float4 q[20]; float f[VPT * DIM]; } wr;
        const float4* p = (const float4*)((const float*)Wop + (size_t)v0 * DIM);
#pragma unroll
        for (int k = 0; k < 20; k++) wr.q[k] = p[k];
#pragma unroll
        for (int j = 0; j < VPT; j++)
#pragma unroll
            for (int d = 0; d < DIM; d++) w[j][d] = wr.f[j * DIM + d];
    }

#pragma unroll
    for (int r = 0; r < RPB; r++) {
        float acc[VPT];
#pragma unroll
        for (int j = 0; j < VPT; j++) acc[j] = 0.f;
#pragma unroll
        for (int d = 0; d < DIM; d++) {
            float h = hrow[r][d];
#pragma unroll
            for (int j = 0; j < VPT; j++) acc[j] += h * w[j][d];
        }
        size_t row = (size_t)blockIdx.y * RPB + r;
        if (isbf) {
            union { uint4 u; bf16 h8[8]; } pk;
#pragma unroll
            for (int j = 0; j < VPT; j++) pk.h8[j] = __float2bfloat16(acc[j]);
            *((uint4*)((bf16*)outp + row * VOC + v0)) = pk.u;
        } else {
            float4 a = make_float4(acc[0], acc[1], acc[2], acc[3]);
            float4 b = make_float4(acc[4], acc[5], acc[6], acc[7]);
            float4* op = (float4*)((float*)outp + row * VOC + v0);
            op[0] = a;
            op[1] = b;
        }
    }
}

// ---------------------------------------------------------------------------
extern "C" void kernel_launch(void* const* d_in, const int* in_sizes, int n_in,
                              void* d_out, int out_size, void* d_ws, size_t ws_size,
                              hipStream_t stream) {
    const int* x = (const int*)d_in[0];
    const void* emb = d_in[1];
    const void* pos = d_in[2];
    const void* Wq  = d_in[3];
    const void* Wk  = d_in[4];
    const void* Wv  = d_in[5];
    const void* Wo  = d_in[6];

    int*   flag = (int*)d_ws;
    float* base = (float*)d_ws + 64;     // 256 B offset keeps alignment
    float* Q = base;                     // 8192*10 f32; O aliases Q (safe)
    float* K = base + 81920;
    float* V = base + 163840;
    float* O = Q;
    // total workspace use: (64 + 3*81920) * 4 B = 983,296 B

    hipLaunchKernelGGL(probe_kernel, dim3(1), dim3(64), 0, stream,
                       (const unsigned short*)emb, flag);
    hipLaunchKernelGGL(qkv_kernel, dim3(NROW / 256), dim3(256), 0, stream,
                       x, emb, pos, Wq, Wk, Wv, flag, Q, K, V);
    hipLaunchKernelGGL(attn_kernel, dim3(NROW / 4), dim3(256), 0, stream,
                       Q, K, V, O);
    hipLaunchKernelGGL(logits_kernel, dim3(16, NROW / RPB), dim3(256), 0,
                       stream, O, Wo, flag, d_out);
}